// Round 4
// baseline (674.447 us; speedup 1.0000x reference)
//
#include <hip/hip_runtime.h>

#define NNODES 100000
#define NEDGES 800000
#define D 128
#define NB1 391  // ceil(NNODES/256)

// ---------------- CSR build ----------------

__global__ __launch_bounds__(256) void k_count(const int* __restrict__ ei,
                                               int* __restrict__ cnt) {
    int e = blockIdx.x * 256 + threadIdx.x;          // grid sized exactly E/256
    atomicAdd(&cnt[ei[e]], 1);
}

__global__ __launch_bounds__(256) void k_scan1(const int* __restrict__ cnt,
                                               int* __restrict__ off,
                                               int* __restrict__ bsum) {
    __shared__ int s[256];
    int t = threadIdx.x;
    int i = blockIdx.x * 256 + t;
    int v = (i < NNODES) ? cnt[i] : 0;
    s[t] = v;
    __syncthreads();
    for (int d = 1; d < 256; d <<= 1) {
        int a = (t >= d) ? s[t - d] : 0;
        __syncthreads();
        s[t] += a;
        __syncthreads();
    }
    if (i < NNODES) off[i] = s[t] - v;               // exclusive within block
    if (t == 255) bsum[blockIdx.x] = s[255];         // block total
}

__global__ __launch_bounds__(512) void k_scan2(int* __restrict__ bsum) {
    __shared__ int s[512];
    int t = threadIdx.x;
    int v = (t < NB1) ? bsum[t] : 0;
    s[t] = v;
    __syncthreads();
    for (int d = 1; d < 512; d <<= 1) {
        int a = (t >= d) ? s[t - d] : 0;
        __syncthreads();
        s[t] += a;
        __syncthreads();
    }
    if (t < NB1) bsum[t] = s[t] - v;                 // exclusive block offsets
}

__global__ __launch_bounds__(256) void k_scan3(int* __restrict__ off,
                                               const int* __restrict__ bsum,
                                               int* __restrict__ cur) {
    int i = blockIdx.x * 256 + threadIdx.x;
    if (i < NNODES) {
        int o = off[i] + bsum[blockIdx.x];
        off[i] = o;
        cur[i] = o;
    }
}

__global__ __launch_bounds__(256) void k_fill(const int* __restrict__ ei,
                                              int* __restrict__ cur,
                                              int* __restrict__ csr) {
    int e = blockIdx.x * 256 + threadIdx.x;
    int r = ei[e];
    int c = ei[NEDGES + e];
    int p = atomicAdd(&cur[r], 1);
    csr[p] = c;
}

// ---------------- W pre-transpose: Wt[k][j] = W[j][k] (128x128) ----------------
// 64 KB once per layer; removes all LDS-transpose conflicts from the hot GEMM.

__global__ __launch_bounds__(256) void k_tr(const float* __restrict__ W,
                                            float* __restrict__ Wt) {
    int i = blockIdx.x * 256 + threadIdx.x;   // grid 64 -> 16384 elements
    int j = i >> 7, k = i & 127;
    Wt[k * D + j] = W[i];
}

// ---------------- GEMM: out[n][j] = sum_k in[n][k] * Wt[k][j] + b[j] ----------------
// Block 512 threads = 128-node x 64-col tile (j-half selected by blockIdx&1).
// Ws = 32KB linear [k][0..63]: staged with coalesced float4 + ds_write_b128
// (conflict-free), read with ds_read_b128 (16 chunks x4 broadcast, conflict-free).
// 4 blocks/CU (128KB LDS), VGPR held to 64 via launch_bounds -> 32 waves/CU.

static __device__ __forceinline__ void fma4(float4& acc, float s, const float4& v) {
    acc.x = fmaf(s, v.x, acc.x);
    acc.y = fmaf(s, v.y, acc.y);
    acc.z = fmaf(s, v.z, acc.z);
    acc.w = fmaf(s, v.w, acc.w);
}

__global__ __launch_bounds__(512, 8) void k_gemm(const float* __restrict__ in,
                                                 const float* __restrict__ Wt,
                                                 const float* __restrict__ bias,
                                                 float* __restrict__ out) {
    __shared__ float Ws[D * 64];
    int t = threadIdx.x;
    int bh = blockIdx.x & 1;        // j-half: columns bh*64 .. bh*64+63
    int nblk = blockIdx.x >> 1;     // 128-node group
    const float4* Wg = (const float4*)Wt;
#pragma unroll
    for (int it = 0; it < 4; ++it) {
        int i4 = it * 512 + t;                   // 0..2047 float4s
        int k = i4 >> 4, cg = i4 & 15;
        ((float4*)Ws)[i4] = Wg[k * 32 + bh * 16 + cg];
    }
    int jl = t & 15;                // j-lane: owns j0 = jl*4 within the half
    int ng = t >> 4;                // 0..31 -> node quad
    int j0 = jl * 4;
    float4 b4 = *(const float4*)(bias + bh * 64 + j0);
    __syncthreads();

    int nb = nblk * 128 + ng * 4;
    if (nb >= NNODES) return;
    const float* p0 = in + (size_t)(nb + 0) * D;
    const float* p1 = in + (size_t)(nb + 1) * D;
    const float* p2 = in + (size_t)(nb + 2) * D;
    const float* p3 = in + (size_t)(nb + 3) * D;
    float4 a0 = b4, a1 = b4, a2 = b4, a3 = b4;
#pragma unroll 4
    for (int k = 0; k < D; k += 4) {
        const float4 w0 = *(const float4*)(Ws + (k + 0) * 64 + j0);
        const float4 w1 = *(const float4*)(Ws + (k + 1) * 64 + j0);
        const float4 w2 = *(const float4*)(Ws + (k + 2) * 64 + j0);
        const float4 w3 = *(const float4*)(Ws + (k + 3) * 64 + j0);
        float4 x0 = *(const float4*)(p0 + k);
        float4 x1 = *(const float4*)(p1 + k);
        float4 x2 = *(const float4*)(p2 + k);
        float4 x3 = *(const float4*)(p3 + k);
        fma4(a0, x0.x, w0); fma4(a0, x0.y, w1); fma4(a0, x0.z, w2); fma4(a0, x0.w, w3);
        fma4(a1, x1.x, w0); fma4(a1, x1.y, w1); fma4(a1, x1.z, w2); fma4(a1, x1.w, w3);
        fma4(a2, x2.x, w0); fma4(a2, x2.y, w1); fma4(a2, x2.z, w2); fma4(a2, x2.w, w3);
        fma4(a3, x3.x, w0); fma4(a3, x3.y, w1); fma4(a3, x3.z, w2); fma4(a3, x3.w, w3);
    }
    int jo = bh * 64 + j0;
    *(float4*)(out + (size_t)(nb + 0) * D + jo) = a0;
    *(float4*)(out + (size_t)(nb + 1) * D + jo) = a1;
    *(float4*)(out + (size_t)(nb + 2) * D + jo) = a2;
    *(float4*)(out + (size_t)(nb + 3) * D + jo) = a3;
}

// ---------------- Message passing: one wave per destination node ----------------
// agg[n][:] = relu( sum_{in-edges} h[src][:] / max(deg,1) ).  Edge loop unrolled
// x4: 4 independent 512B gathers in flight per wave (MLP), vs 1 serial before.

__global__ __launch_bounds__(256) void k_mp(const float* __restrict__ h,
                                            const int* __restrict__ off,
                                            const int* __restrict__ cnt,
                                            const int* __restrict__ csr,
                                            float* __restrict__ agg) {
    int gid = blockIdx.x * 256 + threadIdx.x;
    int node = gid >> 6;
    int lane = threadIdx.x & 63;
    if (node >= NNODES) return;
    int b = off[node];
    int c = cnt[node];
    float ax = 0.f, ay = 0.f;
    int e = 0;
    for (; e + 4 <= c; e += 4) {
        int s0 = csr[b + e + 0];
        int s1 = csr[b + e + 1];
        int s2 = csr[b + e + 2];
        int s3 = csr[b + e + 3];
        float2 v0 = *(const float2*)(h + (size_t)s0 * D + lane * 2);
        float2 v1 = *(const float2*)(h + (size_t)s1 * D + lane * 2);
        float2 v2 = *(const float2*)(h + (size_t)s2 * D + lane * 2);
        float2 v3 = *(const float2*)(h + (size_t)s3 * D + lane * 2);
        ax += (v0.x + v1.x) + (v2.x + v3.x);
        ay += (v0.y + v1.y) + (v2.y + v3.y);
    }
    for (; e < c; ++e) {
        int s = csr[b + e];
        float2 v = *(const float2*)(h + (size_t)s * D + lane * 2);
        ax += v.x;
        ay += v.y;
    }
    float inv = 1.0f / fmaxf((float)c, 1.0f);
    float2 r;
    r.x = fmaxf(ax * inv, 0.f);
    r.y = fmaxf(ay * inv, 0.f);
    *(float2*)(agg + (size_t)node * D + lane * 2) = r;
}

// ---------------- launch ----------------

extern "C" void kernel_launch(void* const* d_in, const int* in_sizes, int n_in,
                              void* d_out, int out_size, void* d_ws, size_t ws_size,
                              hipStream_t stream) {
    const float* x  = (const float*)d_in[0];
    const int*   ei = (const int*)d_in[1];
    const float* W1 = (const float*)d_in[2];
    const float* b1 = (const float*)d_in[3];
    const float* W2 = (const float*)d_in[4];
    const float* b2 = (const float*)d_in[5];
    const float* W3 = (const float*)d_in[6];
    const float* b3 = (const float*)d_in[7];
    float* out = (float*)d_out;

    char* ws = (char*)d_ws;
    int* cnt  = (int*)(ws + 0);
    int* off  = (int*)(ws + (512 << 10));
    int* cur  = (int*)(ws + (1024 << 10));
    int* bsum = (int*)(ws + (1536 << 10));
    int* csr  = (int*)(ws + (2 << 20));                 // 3.2 MB, ends at 5.2 MB
    float* Wt1 = (float*)(ws + ((size_t)6 << 20));      // 64 KB each
    float* Wt2 = (float*)(ws + ((size_t)6 << 20) + 65536);
    float* Wt3 = (float*)(ws + ((size_t)6 << 20) + 131072);
    float* A  = (float*)(ws + ((size_t)8 << 20));       // h0, later agg2
    float* B  = (float*)(ws + ((size_t)64 << 20));      // agg1

    hipMemsetAsync(cnt, 0, NNODES * sizeof(int), stream);
    k_tr<<<64, 256, 0, stream>>>(W1, Wt1);
    k_tr<<<64, 256, 0, stream>>>(W2, Wt2);
    k_tr<<<64, 256, 0, stream>>>(W3, Wt3);
    k_count<<<NEDGES / 256, 256, 0, stream>>>(ei, cnt);
    k_scan1<<<NB1, 256, 0, stream>>>(cnt, off, bsum);
    k_scan2<<<1, 512, 0, stream>>>(bsum);
    k_scan3<<<NB1, 256, 0, stream>>>(off, bsum, cur);
    k_fill<<<NEDGES / 256, 256, 0, stream>>>(ei, cur, csr);

    int gemmGrid = 2 * ((NNODES + 127) / 128);  // 1564
    k_gemm<<<gemmGrid, 512, 0, stream>>>(x, Wt1, b1, A);          // h0
    k_mp<<<NNODES / 4, 256, 0, stream>>>(A, off, cnt, csr, B);    // agg1
    k_gemm<<<gemmGrid, 512, 0, stream>>>(B, Wt2, b2, out);        // h1b
    k_mp<<<NNODES / 4, 256, 0, stream>>>(out, off, cnt, csr, A);  // agg2
    k_gemm<<<gemmGrid, 512, 0, stream>>>(A, Wt3, b3, out);        // final
}

// Round 5
// 506.211 us; speedup vs baseline: 1.3323x; 1.3323x over previous
//
#include <hip/hip_runtime.h>

#define NNODES 100000
#define NEDGES 800000
#define D 128
#define NB1 391  // ceil(NNODES/256)

// ---------------- CSR build ----------------

__global__ __launch_bounds__(256) void k_count(const int* __restrict__ ei,
                                               int* __restrict__ cnt) {
    int e = blockIdx.x * 256 + threadIdx.x;          // grid sized exactly E/256
    atomicAdd(&cnt[ei[e]], 1);
}

__global__ __launch_bounds__(256) void k_scan1(const int* __restrict__ cnt,
                                               int* __restrict__ off,
                                               int* __restrict__ bsum) {
    __shared__ int s[256];
    int t = threadIdx.x;
    int i = blockIdx.x * 256 + t;
    int v = (i < NNODES) ? cnt[i] : 0;
    s[t] = v;
    __syncthreads();
    for (int d = 1; d < 256; d <<= 1) {
        int a = (t >= d) ? s[t - d] : 0;
        __syncthreads();
        s[t] += a;
        __syncthreads();
    }
    if (i < NNODES) off[i] = s[t] - v;               // exclusive within block
    if (t == 255) bsum[blockIdx.x] = s[255];         // block total
}

__global__ __launch_bounds__(512) void k_scan2(int* __restrict__ bsum) {
    __shared__ int s[512];
    int t = threadIdx.x;
    int v = (t < NB1) ? bsum[t] : 0;
    s[t] = v;
    __syncthreads();
    for (int d = 1; d < 512; d <<= 1) {
        int a = (t >= d) ? s[t - d] : 0;
        __syncthreads();
        s[t] += a;
        __syncthreads();
    }
    if (t < NB1) bsum[t] = s[t] - v;                 // exclusive block offsets
}

__global__ __launch_bounds__(256) void k_scan3(int* __restrict__ off,
                                               const int* __restrict__ bsum,
                                               int* __restrict__ cur) {
    int i = blockIdx.x * 256 + threadIdx.x;
    if (i < NNODES) {
        int o = off[i] + bsum[blockIdx.x];
        off[i] = o;
        cur[i] = o;
    }
}

__global__ __launch_bounds__(256) void k_fill(const int* __restrict__ ei,
                                              int* __restrict__ cur,
                                              int* __restrict__ csr) {
    int e = blockIdx.x * 256 + threadIdx.x;
    int r = ei[e];
    int c = ei[NEDGES + e];
    int p = atomicAdd(&cur[r], 1);
    csr[p] = c;
}

// ---------------- W pre-transpose: Wt[k][j] = W[j][k] (128x128) ----------------

__global__ __launch_bounds__(256) void k_tr(const float* __restrict__ W,
                                            float* __restrict__ Wt) {
    int i = blockIdx.x * 256 + threadIdx.x;   // grid 64 -> 16384 elements
    int j = i >> 7, k = i & 127;
    Wt[k * D + j] = W[i];
}

// ---------------- GEMM: out[n][j] = sum_k in[n][k] * Wt[k][j] + b[j] ----------------
// Block 512 threads = 128-node x 64-col tile (j-half = blockIdx&1). Ws = 32KB
// linear [k][0..63]: coalesced float4 + ds_write_b128 staging, conflict-free
// ds_read_b128 (R4: SQ_LDS_BANK_CONFLICT == 0).
// launch_bounds(512,6): 85-VGPR cap -- above the ~60-reg live set (R4's (512,8)
// cap=64 collapsed to VGPR=32 + 130MB scratch spill; R3 proved 64 attainable).
// 3 blocks/CU (96KB LDS), 24 waves/CU.

static __device__ __forceinline__ void fma4(float4& acc, float s, const float4& v) {
    acc.x = fmaf(s, v.x, acc.x);
    acc.y = fmaf(s, v.y, acc.y);
    acc.z = fmaf(s, v.z, acc.z);
    acc.w = fmaf(s, v.w, acc.w);
}

__global__ __launch_bounds__(512, 6) void k_gemm(const float* __restrict__ in,
                                                 const float* __restrict__ Wt,
                                                 const float* __restrict__ bias,
                                                 float* __restrict__ out) {
    __shared__ float Ws[D * 64];
    int t = threadIdx.x;
    int bh = blockIdx.x & 1;        // j-half: columns bh*64 .. bh*64+63
    int nblk = blockIdx.x >> 1;     // 128-node group
    const float4* Wg = (const float4*)Wt;
#pragma unroll
    for (int it = 0; it < 4; ++it) {
        int i4 = it * 512 + t;                   // 0..2047 float4s
        int k = i4 >> 4, cg = i4 & 15;
        ((float4*)Ws)[i4] = Wg[k * 32 + bh * 16 + cg];
    }
    int jl = t & 15;                // j-lane: owns j0 = jl*4 within the half
    int ng = t >> 4;                // 0..31 -> node quad
    int j0 = jl * 4;
    float4 b4 = *(const float4*)(bias + bh * 64 + j0);
    __syncthreads();

    int nb = nblk * 128 + ng * 4;
    if (nb >= NNODES) return;
    const float* p0 = in + (size_t)(nb + 0) * D;
    const float* p1 = in + (size_t)(nb + 1) * D;
    const float* p2 = in + (size_t)(nb + 2) * D;
    const float* p3 = in + (size_t)(nb + 3) * D;
    float4 a0 = b4, a1 = b4, a2 = b4, a3 = b4;
#pragma unroll 4
    for (int k = 0; k < D; k += 4) {
        const float4 w0 = *(const float4*)(Ws + (k + 0) * 64 + j0);
        const float4 w1 = *(const float4*)(Ws + (k + 1) * 64 + j0);
        const float4 w2 = *(const float4*)(Ws + (k + 2) * 64 + j0);
        const float4 w3 = *(const float4*)(Ws + (k + 3) * 64 + j0);
        float4 x0 = *(const float4*)(p0 + k);
        float4 x1 = *(const float4*)(p1 + k);
        float4 x2 = *(const float4*)(p2 + k);
        float4 x3 = *(const float4*)(p3 + k);
        fma4(a0, x0.x, w0); fma4(a0, x0.y, w1); fma4(a0, x0.z, w2); fma4(a0, x0.w, w3);
        fma4(a1, x1.x, w0); fma4(a1, x1.y, w1); fma4(a1, x1.z, w2); fma4(a1, x1.w, w3);
        fma4(a2, x2.x, w0); fma4(a2, x2.y, w1); fma4(a2, x2.z, w2); fma4(a2, x2.w, w3);
        fma4(a3, x3.x, w0); fma4(a3, x3.y, w1); fma4(a3, x3.z, w2); fma4(a3, x3.w, w3);
    }
    int jo = bh * 64 + j0;
    *(float4*)(out + (size_t)(nb + 0) * D + jo) = a0;
    *(float4*)(out + (size_t)(nb + 1) * D + jo) = a1;
    *(float4*)(out + (size_t)(nb + 2) * D + jo) = a2;
    *(float4*)(out + (size_t)(nb + 3) * D + jo) = a3;
}

// ---------------- Message passing: one wave per destination node ----------------
// agg[n][:] = relu( sum_{in-edges} h[src][:] / max(deg,1) ).
// Gather pipeline: 8/4/1 unroll cascade (mean deg = 8) -> up to 8 independent
// 512B gathers in flight per wave.

__global__ __launch_bounds__(256) void k_mp(const float* __restrict__ h,
                                            const int* __restrict__ off,
                                            const int* __restrict__ cnt,
                                            const int* __restrict__ csr,
                                            float* __restrict__ agg) {
    int gid = blockIdx.x * 256 + threadIdx.x;
    int node = gid >> 6;
    int lane = threadIdx.x & 63;
    if (node >= NNODES) return;
    int b = off[node];
    int c = cnt[node];
    float ax = 0.f, ay = 0.f;
    int e = 0;
    for (; e + 8 <= c; e += 8) {
        int s0 = csr[b + e + 0];
        int s1 = csr[b + e + 1];
        int s2 = csr[b + e + 2];
        int s3 = csr[b + e + 3];
        int s4 = csr[b + e + 4];
        int s5 = csr[b + e + 5];
        int s6 = csr[b + e + 6];
        int s7 = csr[b + e + 7];
        float2 v0 = *(const float2*)(h + (size_t)s0 * D + lane * 2);
        float2 v1 = *(const float2*)(h + (size_t)s1 * D + lane * 2);
        float2 v2 = *(const float2*)(h + (size_t)s2 * D + lane * 2);
        float2 v3 = *(const float2*)(h + (size_t)s3 * D + lane * 2);
        float2 v4 = *(const float2*)(h + (size_t)s4 * D + lane * 2);
        float2 v5 = *(const float2*)(h + (size_t)s5 * D + lane * 2);
        float2 v6 = *(const float2*)(h + (size_t)s6 * D + lane * 2);
        float2 v7 = *(const float2*)(h + (size_t)s7 * D + lane * 2);
        ax += ((v0.x + v1.x) + (v2.x + v3.x)) + ((v4.x + v5.x) + (v6.x + v7.x));
        ay += ((v0.y + v1.y) + (v2.y + v3.y)) + ((v4.y + v5.y) + (v6.y + v7.y));
    }
    for (; e + 4 <= c; e += 4) {
        int s0 = csr[b + e + 0];
        int s1 = csr[b + e + 1];
        int s2 = csr[b + e + 2];
        int s3 = csr[b + e + 3];
        float2 v0 = *(const float2*)(h + (size_t)s0 * D + lane * 2);
        float2 v1 = *(const float2*)(h + (size_t)s1 * D + lane * 2);
        float2 v2 = *(const float2*)(h + (size_t)s2 * D + lane * 2);
        float2 v3 = *(const float2*)(h + (size_t)s3 * D + lane * 2);
        ax += (v0.x + v1.x) + (v2.x + v3.x);
        ay += (v0.y + v1.y) + (v2.y + v3.y);
    }
    for (; e < c; ++e) {
        int s = csr[b + e];
        float2 v = *(const float2*)(h + (size_t)s * D + lane * 2);
        ax += v.x;
        ay += v.y;
    }
    float inv = 1.0f / fmaxf((float)c, 1.0f);
    float2 r;
    r.x = fmaxf(ax * inv, 0.f);
    r.y = fmaxf(ay * inv, 0.f);
    *(float2*)(agg + (size_t)node * D + lane * 2) = r;
}

// ---------------- launch ----------------

extern "C" void kernel_launch(void* const* d_in, const int* in_sizes, int n_in,
                              void* d_out, int out_size, void* d_ws, size_t ws_size,
                              hipStream_t stream) {
    const float* x  = (const float*)d_in[0];
    const int*   ei = (const int*)d_in[1];
    const float* W1 = (const float*)d_in[2];
    const float* b1 = (const float*)d_in[3];
    const float* W2 = (const float*)d_in[4];
    const float* b2 = (const float*)d_in[5];
    const float* W3 = (const float*)d_in[6];
    const float* b3 = (const float*)d_in[7];
    float* out = (float*)d_out;

    char* ws = (char*)d_ws;
    int* cnt  = (int*)(ws + 0);
    int* off  = (int*)(ws + (512 << 10));
    int* cur  = (int*)(ws + (1024 << 10));
    int* bsum = (int*)(ws + (1536 << 10));
    int* csr  = (int*)(ws + (2 << 20));                 // 3.2 MB, ends at 5.2 MB
    float* Wt1 = (float*)(ws + ((size_t)6 << 20));      // 64 KB each
    float* Wt2 = (float*)(ws + ((size_t)6 << 20) + 65536);
    float* Wt3 = (float*)(ws + ((size_t)6 << 20) + 131072);
    float* A  = (float*)(ws + ((size_t)8 << 20));       // h0, later agg2
    float* B  = (float*)(ws + ((size_t)64 << 20));      // agg1

    hipMemsetAsync(cnt, 0, NNODES * sizeof(int), stream);
    k_tr<<<64, 256, 0, stream>>>(W1, Wt1);
    k_tr<<<64, 256, 0, stream>>>(W2, Wt2);
    k_tr<<<64, 256, 0, stream>>>(W3, Wt3);
    k_count<<<NEDGES / 256, 256, 0, stream>>>(ei, cnt);
    k_scan1<<<NB1, 256, 0, stream>>>(cnt, off, bsum);
    k_scan2<<<1, 512, 0, stream>>>(bsum);
    k_scan3<<<NB1, 256, 0, stream>>>(off, bsum, cur);
    k_fill<<<NEDGES / 256, 256, 0, stream>>>(ei, cur, csr);

    int gemmGrid = 2 * ((NNODES + 127) / 128);  // 1564
    k_gemm<<<gemmGrid, 512, 0, stream>>>(x, Wt1, b1, A);          // h0
    k_mp<<<NNODES / 4, 256, 0, stream>>>(A, off, cnt, csr, B);    // agg1
    k_gemm<<<gemmGrid, 512, 0, stream>>>(B, Wt2, b2, out);        // h1b
    k_mp<<<NNODES / 4, 256, 0, stream>>>(out, off, cnt, csr, A);  // agg2
    k_gemm<<<gemmGrid, 512, 0, stream>>>(A, Wt3, b3, out);        // final
}